// Round 9
// baseline (62.432 us; speedup 1.0000x reference)
//
#include <hip/hip_runtime.h>

// CorrelationAlign: out[b, a*63+c, i, j] = in[b, (a+i-31)*32 + (c+j-31), i, j]
//   valid iff 0 <= a+i-31 < 32 and 0 <= c+j-31 < 32, else 0.  b=16, h=w=32.
//
// FINAL (R1 structure, 58.8us = 5.45 TB/s effective on 320 MB compulsory
// traffic): one block per (b, a, i), LDS diagonal transpose.
//   - Input tile in[b, p*32+q, i, j] (p = a+i-31 fixed per block) = 32
//     contiguous 128B rows, each fetched exactly once chip-wide.
//   - LDS stride 33: diagonal read (q = c+j-31) is 2-way bank aliasing (free).
//   - Output: 63 c-rows of 128B float4 teeth @ 4KB stride; the 32 i-sibling
//     blocks are adjacent in dispatch order and collectively fill each 4KB
//     row with full 128B L2 lines.
// Falsified alternatives (R3-R7): XCD swizzle, nt stores, 512B/1KB store
// spans (any occupancy), barrier-free wave-private tiles — all <= R1.

#define LDSS 33   // padded LDS row stride (floats)

__global__ __launch_bounds__(256) void CorrelationAlign_kernel(
    const float* __restrict__ in, float* __restrict__ out) {
  __shared__ float tile[32 * LDSS];  // 4224 B

  const int bid = blockIdx.x;         // ((b*63 + a) * 32 + i)
  const int i  = bid & 31;
  const int ba = bid >> 5;
  const int a  = ba % 63;
  const int b  = ba / 63;
  const int p  = a + i - 31;
  const int t  = threadIdx.x;

  float* outbase = out + (size_t)(b * 3969 + a * 63) * 1024 + i * 32;

  if ((unsigned)p < 32u) {
    // ---- load 32x32 input tile: row q is 128B contiguous ----
    const float* inbase = in + (size_t)(b * 1024 + p * 32) * 1024 + i * 32;
    {
      const int q  = t >> 3;          // 0..31
      const int j0 = (t & 7) * 4;     // 0,4,...,28
      const float4 v =
          *reinterpret_cast<const float4*>(inbase + (size_t)q * 1024 + j0);
      float* row = &tile[q * LDSS + j0];
      row[0] = v.x; row[1] = v.y; row[2] = v.z; row[3] = v.w;
    }
    __syncthreads();

    // ---- emit 63 output rows (c), 8 float4 each: diagonal LDS read ----
    for (int task = t; task < 63 * 8; task += 256) {
      const int c  = task >> 3;
      const int j0 = (task & 7) * 4;
      float4 v;
      float* vp = reinterpret_cast<float*>(&v);
#pragma unroll
      for (int k = 0; k < 4; ++k) {
        const int j = j0 + k;
        const int q = c + j - 31;
        vp[k] = ((unsigned)q < 32u) ? tile[q * LDSS + j] : 0.0f;
      }
      *reinterpret_cast<float4*>(outbase + (size_t)c * 1024 + j0) = v;
    }
  } else {
    // ---- p out of range: whole (c, j) plane for this (b, a, i) is zero ----
    const float4 z = make_float4(0.f, 0.f, 0.f, 0.f);
    for (int task = t; task < 63 * 8; task += 256) {
      const int c  = task >> 3;
      const int j0 = (task & 7) * 4;
      *reinterpret_cast<float4*>(outbase + (size_t)c * 1024 + j0) = z;
    }
  }
}

extern "C" void kernel_launch(void* const* d_in, const int* in_sizes, int n_in,
                              void* d_out, int out_size, void* d_ws,
                              size_t ws_size, hipStream_t stream) {
  (void)in_sizes; (void)n_in; (void)out_size; (void)d_ws; (void)ws_size;
  const float* in = (const float*)d_in[0];
  float* out = (float*)d_out;
  const int grid = 16 * 63 * 32;  // one block per (b, a, i)
  CorrelationAlign_kernel<<<grid, 256, 0, stream>>>(in, out);
}